// Round 6
// baseline (571.666 us; speedup 1.0000x reference)
//
#include <hip/hip_runtime.h>
#include <hip/hip_bf16.h>

#define NN 8192
#define FIN 512
#define FOUT 256
#define SLICES 8
#define JLEN (NN / SLICES)      // 1024
#define NCHUNK (JLEN / 64)      // 16

typedef __attribute__((ext_vector_type(8))) short short8;
typedef __attribute__((ext_vector_type(4))) float float4v;
typedef __attribute__((ext_vector_type(16))) float float16v;

__device__ __forceinline__ short f2bf(float f) {
    union { float f; unsigned u; } v; v.f = f;
    unsigned r = (v.u + 0x7FFFu + ((v.u >> 16) & 1u)) >> 16;
    return (short)r;
}

// ---------------- Kernel 0: Wt[n][k] = bf16(W[k][n]), tiled transpose ----------------
__global__ __launch_bounds__(256) void wt_kernel(const float* __restrict__ W,
                                                 short* __restrict__ Wt) {
    __shared__ short tile[32][33];
    int tx = threadIdx.x & 31, ty = threadIdx.x >> 5;
    int k0 = blockIdx.x * 32, n0 = blockIdx.y * 32;
#pragma unroll
    for (int r = 0; r < 32; r += 8)
        tile[ty + r][tx] = f2bf(W[(size_t)(k0 + ty + r) * FOUT + n0 + tx]);
    __syncthreads();
#pragma unroll
    for (int r = 0; r < 32; r += 8)
        Wt[(size_t)(n0 + ty + r) * FIN + k0 + tx] = tile[tx][ty + r];
}

// ---------------- Kernel 1: h_t[n][m] = bf16((x@W)[m][n]); fused f_src/f_dst ----------------
__global__ __launch_bounds__(256) void h_kernel(const float* __restrict__ x,
                                                const short* __restrict__ Wt,
                                                const float* __restrict__ a,
                                                short* __restrict__ h_t,
                                                float* __restrict__ f_src,
                                                float* __restrict__ f_dst) {
    int wave = (blockIdx.x << 2) + (threadIdx.x >> 6);
    int lane = threadIdx.x & 63;
    int m0 = (wave & 511) << 4;
    int n0 = (wave >> 9) << 6;
    int lr = lane & 15, lq = lane >> 4;

    const float* xrow = x + (size_t)(m0 + lr) * FIN + lq * 8;
    const short* wbase = Wt + (size_t)(n0 + lr) * FIN + lq * 8;

    float4v acc[4] = {};
    for (int k0 = 0; k0 < FIN; k0 += 32) {
        float4v xa = *(const float4v*)(xrow + k0);
        float4v xb = *(const float4v*)(xrow + k0 + 4);
        short8 av;
        av[0] = f2bf(xa[0]); av[1] = f2bf(xa[1]); av[2] = f2bf(xa[2]); av[3] = f2bf(xa[3]);
        av[4] = f2bf(xb[0]); av[5] = f2bf(xb[1]); av[6] = f2bf(xb[2]); av[7] = f2bf(xb[3]);
#pragma unroll
        for (int ct = 0; ct < 4; ct++) {
            short8 bv = *(const short8*)(wbase + (size_t)ct * 16 * FIN + k0);
            acc[ct] = __builtin_amdgcn_mfma_f32_16x16x32_bf16(av, bv, acc[ct], 0, 0, 0);
        }
    }
    float s_part[4] = {0.f, 0.f, 0.f, 0.f};
    float d_part[4] = {0.f, 0.f, 0.f, 0.f};
#pragma unroll
    for (int ct = 0; ct < 4; ct++) {
        int n = n0 + ct * 16 + lr;
        float al = a[n], ar = a[FOUT + n];
#pragma unroll
        for (int reg = 0; reg < 4; reg++) {
            float hv = acc[ct][reg];
            s_part[reg] = fmaf(hv, al, s_part[reg]);
            d_part[reg] = fmaf(hv, ar, d_part[reg]);
            h_t[(size_t)n * NN + (m0 + lq * 4 + reg)] = f2bf(hv);
        }
    }
#pragma unroll
    for (int off = 1; off < 16; off <<= 1) {
#pragma unroll
        for (int reg = 0; reg < 4; reg++) {
            s_part[reg] += __shfl_xor(s_part[reg], off);
            d_part[reg] += __shfl_xor(d_part[reg], off);
        }
    }
    const float LOG2E = 1.4426950408889634f;
    if (lr == 0) {
#pragma unroll
        for (int reg = 0; reg < 4; reg++) {
            atomicAdd(&f_src[m0 + lq * 4 + reg], s_part[reg] * LOG2E);
            atomicAdd(&f_dst[m0 + lq * 4 + reg], d_part[reg] * LOG2E);
        }
    }
}

// ---------------- Kernel 2: fused pack + masked-softmax-numerator @ h ----------------
// Grid (64 rowgroups, 8 slices) = 512 blocks = 2/CU. Block 512 thr = 8 waves.
// Phase A: stream block's adj slice (128 rows x 1024 j = 512 KB) coalesced,
//          __ballot -> u64 masks in LDS (each adj element read ONCE chip-wide).
// Phase B: R5 compute loop; masks from LDS (stride-17 u64 = 2-way alias, free),
//          Ht single-buffered, chunk c+1 register-prefetched a compute-phase ahead.
__global__ __launch_bounds__(512, 4) void gat_kernel(const int* __restrict__ adj,
                                                     const short* __restrict__ h_t,
                                                     const float* __restrict__ f_src,
                                                     const float* __restrict__ f_dst,
                                                     float* __restrict__ Opart,
                                                     float* __restrict__ lpart) {
    __shared__ short Ht[256 * 64];                    // 32 KB, swizzled, single buffer
    __shared__ unsigned long long msk[128 * 17];      // 17 KB, stride 17 (odd)

    const int t = threadIdx.x;
    const int lane = t & 63;
    const int w = t >> 6;
    const int l31 = lane & 31, lq = lane >> 5;
    const int wr = w & 3, wc = w >> 2;                // rowgroup 0..3, featgroup 0..1
    const int i0 = blockIdx.x * 128;
    const int slice = blockIdx.y;
    const int jbase = slice * JLEN;
    const int r = i0 + wr * 32 + l31;
    const int rsw = l31 & 7;                          // Ht read-side swizzle key

    // ---- phase A: pack this block's adj slice to LDS masks ----
    {
        const int* ab = adj + (size_t)(i0 + (w << 4)) * NN + jbase + lane;
#pragma unroll 8
        for (int u = 0; u < 256; ++u) {               // wave w: rows [w*16, w*16+16)
            int row = u >> 4, c = u & 15;
            int v = ab[(size_t)row * NN + c * 64];
            unsigned long long m = __ballot(v != 0);
            if (lane == 0) msk[((w << 4) + row) * 17 + c] = m;
        }
    }

    const float fs = f_src[r];
    const float* fdL = f_dst + jbase + lq * 8;

    // staging role: thread t stages feat sf = t>>1, col-quads sq0..sq0+3
    const int sf = t >> 1, sq0 = (t & 1) * 4;
    const short* hrow = h_t + (size_t)sf * NN + jbase + sq0 * 8;
    const int fsw = sf & 7;                           // stage-side swizzle key
    short* HtW = &Ht[sf * 64];

    float16v acc[4] = {};
    float lp = 0.f;

    // preload chunk 0 into registers
    short8 s0 = *(const short8*)(hrow + 0);
    short8 s1 = *(const short8*)(hrow + 8);
    short8 s2 = *(const short8*)(hrow + 16);
    short8 s3 = *(const short8*)(hrow + 24);
    __syncthreads();                                  // masks committed

    for (int c = 0; c < NCHUNK; ++c) {
        // write staged regs -> Ht
        *(short8*)(HtW + (((sq0 + 0) ^ fsw) << 3)) = s0;
        *(short8*)(HtW + (((sq0 + 1) ^ fsw) << 3)) = s1;
        *(short8*)(HtW + (((sq0 + 2) ^ fsw) << 3)) = s2;
        *(short8*)(HtW + (((sq0 + 3) ^ fsw) << 3)) = s3;
        __syncthreads();                              // Ht[c] visible

        // register-prefetch chunk c+1 (consumed after the whole compute phase)
        const int cn = (c + 1 < NCHUNK) ? c + 1 : c;
        s0 = *(const short8*)(hrow + cn * 64 + 0);
        s1 = *(const short8*)(hrow + cn * 64 + 8);
        s2 = *(const short8*)(hrow + cn * 64 + 16);
        s3 = *(const short8*)(hrow + cn * 64 + 24);

        const unsigned long long bm = msk[(wr * 32 + l31) * 17 + c];
        const unsigned bmlo = (unsigned)bm, bmhi = (unsigned)(bm >> 32);
#pragma unroll
        for (int kk = 0; kk < 4; ++kk) {
            const int jo = c * 64 + kk * 16;
            float4 f0 = *(const float4*)(fdL + jo);
            float4 f1 = *(const float4*)(fdL + jo + 4);
            unsigned w32 = (kk < 2) ? bmlo : bmhi;
            unsigned m8 = (w32 >> ((kk & 1) * 16 + lq * 8)) & 0xffu;

            short8 af;
            const float* ff0 = (const float*)&f0;
            const float* ff1 = (const float*)&f1;
#pragma unroll
            for (int q = 0; q < 8; ++q) {
                float fdv = (q < 4) ? ff0[q] : ff1[q - 4];
                float y = fs + fdv;
                y = fmaxf(y, 0.2f * y);               // leaky_relu (log2-scaled domain)
                float e = exp2f(y);
                float p = (m8 & (1u << q)) ? e : 0.f;
                lp += p;
                af[q] = f2bf(p);
            }
            const int cb = ((kk * 2 + lq) ^ rsw) << 3;
#pragma unroll
            for (int nt = 0; nt < 4; nt++) {
                const int feat = wc * 128 + nt * 32 + l31;
                short8 b = *(const short8*)(&Ht[0] + feat * 64 + cb);
                acc[nt] = __builtin_amdgcn_mfma_f32_32x32x16_bf16(af, b, acc[nt], 0, 0, 0);
            }
        }
        __syncthreads();                              // reads done before next overwrite
    }

    // ---- partial row-sum l (featgroup 0 only) ----
    lp += __shfl_xor(lp, 32);
    if (wc == 0 && lq == 0) lpart[(size_t)slice * NN + r] = lp;

    // ---- partial O: C/D 32x32 mapping: col=l31, row=(reg&3)+8*(reg>>2)+4*lq ----
    float* ob = Opart + ((size_t)slice * NN + i0 + wr * 32) * FOUT + wc * 128;
#pragma unroll
    for (int nt = 0; nt < 4; nt++) {
        int n = nt * 32 + l31;
#pragma unroll
        for (int reg = 0; reg < 16; reg++) {
            int row = (reg & 3) + 8 * (reg >> 2) + 4 * lq;
            ob[(size_t)row * FOUT + n] = acc[nt][reg];
        }
    }
}

// ---------------- Kernel 3: combine partials: out = sum_s O_s / sum_s l_s ----------------
__global__ __launch_bounds__(256) void combine_kernel(const float* __restrict__ Opart,
                                                      const float* __restrict__ lpart,
                                                      float* __restrict__ out) {
    int i = blockIdx.x, n = threadIdx.x;
    float o = 0.f, l = 0.f;
#pragma unroll
    for (int s = 0; s < SLICES; s++) {
        o += Opart[((size_t)s * NN + i) * FOUT + n];
        l += lpart[(size_t)s * NN + i];
    }
    out[(size_t)i * FOUT + n] = o / l;
}

extern "C" void kernel_launch(void* const* d_in, const int* in_sizes, int n_in,
                              void* d_out, int out_size, void* d_ws, size_t ws_size,
                              hipStream_t stream) {
    const float* x   = (const float*)d_in[0];
    const int*   adj = (const int*)d_in[1];
    const float* W   = (const float*)d_in[2];
    const float* a   = (const float*)d_in[3];
    float* out = (float*)d_out;

    char* ws = (char*)d_ws;
    short* h_t   = (short*)ws;                                   // 0..4 MB
    short* Wt    = (short*)(ws + (4u << 20));                    // 256 KB
    float* f_src = (float*)(ws + (4u << 20) + (256u << 10));     // 32 KB
    float* f_dst = (float*)(ws + (4u << 20) + (288u << 10));     // 32 KB
    float* lpart = (float*)(ws + (4u << 20) + (320u << 10));     // 256 KB
    float* Opart = (float*)(ws + (16u << 20));                   // 64 MB (8 slices)

    hipMemsetAsync(f_src, 0, 2 * NN * sizeof(float), stream);
    wt_kernel<<<dim3(FIN / 32, FOUT / 32), 256, 0, stream>>>(W, Wt);
    h_kernel<<<512, 256, 0, stream>>>(x, Wt, a, h_t, f_src, f_dst);
    gat_kernel<<<dim3(NN / 128, SLICES), 512, 0, stream>>>(adj, h_t, f_src, f_dst,
                                                           Opart, lpart);
    combine_kernel<<<NN, 256, 0, stream>>>(Opart, lpart, out);
}